// Round 1
// baseline (189.648 us; speedup 1.0000x reference)
//
#include <hip/hip_runtime.h>
#include <hip/hip_bf16.h>

#define D_ 128
#define N_ 8192
#define K_ 256

typedef __attribute__((ext_vector_type(8))) short sh8;   // 8 bf16 = 4 VGPRs
typedef __attribute__((ext_vector_type(4))) float f4;    // 4 fp32

__device__ __forceinline__ unsigned short f2bf(float f) {
  union { float f; unsigned u; } x; x.f = f;
  unsigned r = x.u + 0x7fffu + ((x.u >> 16) & 1u);       // RNE
  return (unsigned short)(r >> 16);
}

// ---------------------------------------------------------------------------
// prep_x: X (fp32 [D][N]) -> Xbt (bf16 [N][D]) transpose, and copy X -> out rows 0..D-1
// grid (N/64, D/64), block 256
__global__ void prep_x_k(const float* __restrict__ X, float* __restrict__ out,
                         unsigned short* __restrict__ Xbt) {
  __shared__ float tile[64][65];
  const int n0 = blockIdx.x * 64;
  const int e0 = blockIdx.y * 64;
  const int t = threadIdx.x;
  const int col = t & 63;
  const int r4 = t >> 6;
  for (int rr = 0; rr < 64; rr += 4) {
    int e = rr + r4;
    float v = X[(size_t)(e0 + e) * N_ + n0 + col];
    tile[e][col] = v;
    out[(size_t)(e0 + e) * N_ + n0 + col] = v;   // exact fp32 copy of X
  }
  __syncthreads();
  const int chunk = t & 15;
  for (int iter = 0; iter < 4; ++iter) {
    int nl = iter * 16 + (t >> 4);
    ushort4 w;
    w.x = f2bf(tile[chunk * 4 + 0][nl]);
    w.y = f2bf(tile[chunk * 4 + 1][nl]);
    w.z = f2bf(tile[chunk * 4 + 2][nl]);
    w.w = f2bf(tile[chunk * 4 + 3][nl]);
    *(ushort4*)&Xbt[(size_t)(n0 + nl) * D_ + e0 + chunk * 4] = w;
  }
}

// ---------------------------------------------------------------------------
// prep_a: N_A (fp32 [D][D][K], layout d,e,c) -> Ab (bf16 [K][D][D], layout c,d,e)
// grid (K/64, D/64, D), block 256
__global__ void prep_a_k(const float* __restrict__ NA, unsigned short* __restrict__ Ab) {
  __shared__ float tile[64][65];   // [e][c]
  const int c0 = blockIdx.x * 64;
  const int e0 = blockIdx.y * 64;
  const int d  = blockIdx.z;
  const int t = threadIdx.x;
  const int cc = t & 63;
  const int r4 = t >> 6;
  const size_t dbase = (size_t)d * D_ * K_;
  for (int rr = 0; rr < 64; rr += 4) {
    int e = rr + r4;
    tile[e][cc] = NA[dbase + (size_t)(e0 + e) * K_ + c0 + cc];
  }
  __syncthreads();
  const int chunk = t & 15;
  for (int iter = 0; iter < 4; ++iter) {
    int cl = iter * 16 + (t >> 4);
    ushort4 w;
    w.x = f2bf(tile[chunk * 4 + 0][cl]);
    w.y = f2bf(tile[chunk * 4 + 1][cl]);
    w.z = f2bf(tile[chunk * 4 + 2][cl]);
    w.w = f2bf(tile[chunk * 4 + 3][cl]);
    *(ushort4*)&Ab[(size_t)(c0 + cl) * D_ * D_ + (size_t)d * D_ + e0 + chunk * 4] = w;
  }
}

// ---------------------------------------------------------------------------
// amu: Amut[c][d] = sum_e N_A[d][e][c] * N_mu[e][c]   (fp32, exact)
// grid (D), block (K)
__global__ void amu_k(const float* __restrict__ NA, const float* __restrict__ Nmu,
                      float* __restrict__ Amut) {
  const int d = blockIdx.x;
  const int c = threadIdx.x;
  float s = 0.f;
  const size_t dbase = (size_t)d * D_ * K_;
  for (int e = 0; e < D_; ++e)
    s += NA[dbase + (size_t)e * K_ + c] * Nmu[(size_t)e * K_ + c];
  Amut[(size_t)c * D_ + d] = s;
}

// ---------------------------------------------------------------------------
// main: for each (n-tile of 128, c-chunk of 32):
//   sq[c][n] = sum_d (sum_e A[d,e,c] X[e,n] - Amu[d,c])^2
// grid (N/128, K/32), block 256 (4 waves). Wave w: d in [w*32, w*32+32), j in [0,128).
__global__ __launch_bounds__(256, 2) void main_k(
    const unsigned short* __restrict__ Ab, const unsigned short* __restrict__ Xbt,
    const float* __restrict__ Amut, float* __restrict__ sqws) {
  __shared__ float sqred[2][4][128];
  const int t = threadIdx.x;
  const int w = t >> 6;
  const int L = t & 63;
  const int m = L & 15;        // MFMA row/col lane index
  const int q = L >> 4;        // quad
  const int n0 = blockIdx.x * 128;
  const int c0 = blockIdx.y * 32;

  // X B-fragments in registers for entire c-loop: B[k=e][n=j]; lane holds
  // n = jt*16+m, k = ks*32 + q*8 + i  -> contiguous 16B from Xbt[n][e]
  sh8 xf[8][4];
#pragma unroll
  for (int jt = 0; jt < 8; ++jt)
#pragma unroll
    for (int ks = 0; ks < 4; ++ks)
      xf[jt][ks] = *(const sh8*)&Xbt[(size_t)(n0 + jt * 16 + m) * D_ + ks * 32 + q * 8];

  const f4 zero = {0.f, 0.f, 0.f, 0.f};

  for (int ci = 0; ci < 32; ++ci) {
    const int c = c0 + ci;
    const unsigned short* Ap = Ab + (size_t)c * D_ * D_;

    f4 acc[2][8];
#pragma unroll
    for (int dt = 0; dt < 2; ++dt)
#pragma unroll
      for (int jt = 0; jt < 8; ++jt) acc[dt][jt] = zero;

#pragma unroll
    for (int ks = 0; ks < 4; ++ks) {
      sh8 a0 = *(const sh8*)&Ap[(size_t)(w * 32 + m) * D_ + ks * 32 + q * 8];
      sh8 a1 = *(const sh8*)&Ap[(size_t)(w * 32 + 16 + m) * D_ + ks * 32 + q * 8];
#pragma unroll
      for (int jt = 0; jt < 8; ++jt) {
        acc[0][jt] = __builtin_amdgcn_mfma_f32_16x16x32_bf16(a0, xf[jt][ks], acc[0][jt], 0, 0, 0);
        acc[1][jt] = __builtin_amdgcn_mfma_f32_16x16x32_bf16(a1, xf[jt][ks], acc[1][jt], 0, 0, 0);
      }
    }

    // epilogue: subtract Amu, square, reduce over d
    // C/D layout: col j = jt*16 + m, row d = (dtile*16) + q*4 + r
    f4 amu0 = *(const f4*)&Amut[(size_t)c * D_ + w * 32 + q * 4];
    f4 amu1 = *(const f4*)&Amut[(size_t)c * D_ + w * 32 + 16 + q * 4];
    float ps[8];
#pragma unroll
    for (int jt = 0; jt < 8; ++jt) {
      float s = 0.f;
#pragma unroll
      for (int r = 0; r < 4; ++r) {
        float v0 = acc[0][jt][r] - amu0[r];
        float v1 = acc[1][jt][r] - amu1[r];
        s += v0 * v0 + v1 * v1;
      }
      s += __shfl_xor(s, 16, 64);   // combine quads (d rows q*4..q*4+3)
      s += __shfl_xor(s, 32, 64);
      ps[jt] = s;                   // now full sum over this wave's 32 d rows
    }
    // lane (q,m) stores j = 2q*16+m and (2q+1)*16+m (avoid dynamic reg indexing)
    float sel0 = (q == 0) ? ps[0] : (q == 1) ? ps[2] : (q == 2) ? ps[4] : ps[6];
    float sel1 = (q == 0) ? ps[1] : (q == 1) ? ps[3] : (q == 2) ? ps[5] : ps[7];
    const int buf = ci & 1;
    sqred[buf][w][q * 32 + m] = sel0;
    sqred[buf][w][q * 32 + 16 + m] = sel1;
    __syncthreads();
    if (t < 128) {
      float s = sqred[buf][0][t] + sqred[buf][1][t] + sqred[buf][2][t] + sqred[buf][3][t];
      sqws[(size_t)c * N_ + n0 + t] = s;
    }
  }
}

// ---------------------------------------------------------------------------
// softmax over c per n; writes Pi to out rows D_..D_+K_-1
// grid (N/64), block 256. thread t: n_loc = t&63, c-group = t>>6 (64 c each)
__global__ __launch_bounds__(256) void softmax_k(const float* __restrict__ sqws,
                                                 const float* __restrict__ gptr,
                                                 float* __restrict__ out) {
  __shared__ float s_ld[K_ * 64];   // [c][n_loc] 64 KB
  __shared__ float red[4][64];
  __shared__ float red2[4][64];
  const int t = threadIdx.x;
  const int n0 = blockIdx.x * 64;
  const float gamma = *gptr;
  // load all sq for 64 n
  for (int it = 0; it < 64; ++it) {
    int c = it * 4 + (t >> 6);
    s_ld[c * 64 + (t & 63)] = sqws[(size_t)c * N_ + n0 + (t & 63)];
  }
  __syncthreads();
  const int nl = t & 63;
  const int cg = t >> 6;
  // pass 1: max of gamma*s over this thread's 64 c
  float mxp = -1e30f;
  for (int cc = 0; cc < 64; ++cc) {
    float v = s_ld[(cg * 64 + cc) * 64 + nl];
    mxp = fmaxf(mxp, gamma * v);
  }
  red[cg][nl] = mxp;
  __syncthreads();
  float mx = fmaxf(fmaxf(red[0][nl], red[1][nl]), fmaxf(red[2][nl], red[3][nl]));
  // pass 2: exp and partial sum
  float z = 0.f;
  for (int cc = 0; cc < 64; ++cc) {
    int idx = (cg * 64 + cc) * 64 + nl;
    float e = __expf(gamma * s_ld[idx] - mx);
    s_ld[idx] = e;
    z += e;
  }
  red2[cg][nl] = z;
  __syncthreads();
  float zz = red2[0][nl] + red2[1][nl] + red2[2][nl] + red2[3][nl];
  float rz = 1.f / zz;
  // pass 3: write Pi
  for (int cc = 0; cc < 64; ++cc) {
    int c = cg * 64 + cc;
    out[(size_t)(D_ + c) * N_ + n0 + nl] = s_ld[c * 64 + nl] * rz;
  }
}

// ---------------------------------------------------------------------------
extern "C" void kernel_launch(void* const* d_in, const int* in_sizes, int n_in,
                              void* d_out, int out_size, void* d_ws, size_t ws_size,
                              hipStream_t stream) {
  const float* X   = (const float*)d_in[0];
  const float* NA  = (const float*)d_in[1];
  const float* Nmu = (const float*)d_in[2];
  const float* g   = (const float*)d_in[3];
  float* out = (float*)d_out;
  char* ws = (char*)d_ws;

  unsigned short* Xbt = (unsigned short*)(ws);                 // 2 MB
  unsigned short* Ab  = (unsigned short*)(ws + 2097152);       // 8.39 MB
  float* Amut         = (float*)(ws + 10485760);               // 128 KB
  float* sqws         = (float*)(ws + 10616832);               // 8.39 MB

  hipLaunchKernelGGL(prep_x_k, dim3(N_ / 64, D_ / 64), dim3(256), 0, stream, X, out, Xbt);
  hipLaunchKernelGGL(prep_a_k, dim3(K_ / 64, D_ / 64, D_), dim3(256), 0, stream, NA, Ab);
  hipLaunchKernelGGL(amu_k, dim3(D_), dim3(K_), 0, stream, NA, Nmu, Amut);
  hipLaunchKernelGGL(main_k, dim3(N_ / 128, K_ / 32), dim3(256), 0, stream, Ab, Xbt, Amut, sqws);
  hipLaunchKernelGGL(softmax_k, dim3(N_ / 64), dim3(256), 0, stream, sqws, g, out);
}